// Round 6
// baseline (524.610 us; speedup 1.0000x reference)
//
#include <hip/hip_runtime.h>
#include <hip/hip_bf16.h>

// GAT layer, N=8192, F=128.
//   k0:  u = W@a1, v = W@a2                    (fp32, trivial)
//   k1:  Wh = h@W -> WhT2 (bf16, fragment-major [kappa][f][k32], kappa
//        stride 4096 shorts = 128*32);  e_src = h@u, e_dst = h@v (fp32)
//   k1b: adj (256 MB) -> natural-order bitmask (8 MB). Pure streaming.
//   k2:  fused masked-softmax(P) @ Wh via MFMA. K-loop reads ONLY
//        register-held bitmask + L1 e_dst + L2 WhT2. No barriers.
//        Wave = 32 rows x 128 cols; per-seg partials -> ws.
//   k3:  out = (sum_seg num) / (sum_seg den)
//
// ws: 0-2M WhT2 | 2M u,v | 2M+1K e_src | +32K e_dst | 3M bits (8MB)
//     | 16M num_ws (16 x 4MB) | 80M den_ws (512KB)

#define NN 8192
#define FF 128
#define SEGS 16
#define JSEG (NN / SEGS)     // 512

typedef __bf16 bf16x8 __attribute__((ext_vector_type(8)));
typedef float floatx4 __attribute__((ext_vector_type(4)));

__device__ __forceinline__ unsigned short f2b(float f) {
    unsigned int u = __float_as_uint(f);
    return (unsigned short)((u + 0x7FFFu + ((u >> 16) & 1u)) >> 16);
}
__device__ __forceinline__ unsigned int pk2(float a, float b) {
    return (unsigned int)f2b(a) | ((unsigned int)f2b(b) << 16);
}

// ---------------- k0 ----------------
__global__ __launch_bounds__(128) void k0_uv(const float* __restrict__ W,
                                             const float* __restrict__ a,
                                             float* __restrict__ u,
                                             float* __restrict__ v) {
    int k = blockIdx.x, t = threadIdx.x;
    float wv = W[k * FF + t];
    float p1 = wv * a[t];
    float p2 = wv * a[FF + t];
    for (int off = 32; off; off >>= 1) {
        p1 += __shfl_down(p1, off);
        p2 += __shfl_down(p2, off);
    }
    __shared__ float r[4];
    if ((t & 63) == 0) { r[(t >> 6) * 2] = p1; r[(t >> 6) * 2 + 1] = p2; }
    __syncthreads();
    if (t == 0) { u[k] = r[0] + r[2]; v[k] = r[1] + r[3]; }
}

// ---------------- k1 ----------------
__global__ __launch_bounds__(256) void k1_wh(const float* __restrict__ h,
                                             const float* __restrict__ W,
                                             const float* __restrict__ u,
                                             const float* __restrict__ v,
                                             unsigned short* __restrict__ WhT2,
                                             float* __restrict__ e_src,
                                             float* __restrict__ e_dst) {
    __shared__ float hL[32 * 132];
    __shared__ float wL[128 * 132];
    __shared__ float uL[128], vL[128];
    __shared__ unsigned short tL[128 * 40];

    int t = threadIdx.x;
    int i0 = blockIdx.x * 32;

    {
        int row = t >> 3, c = (t & 7) * 16;
        const float4* s = (const float4*)&h[(i0 + row) * FF + c];
        float4* d = (float4*)&hL[row * 132 + c];
        #pragma unroll
        for (int j = 0; j < 4; j++) d[j] = s[j];
    }
    {
        int row = t >> 1, c = (t & 1) * 64;
        const float4* s = (const float4*)&W[row * FF + c];
        float4* d = (float4*)&wL[row * 132 + c];
        #pragma unroll
        for (int j = 0; j < 16; j++) d[j] = s[j];
    }
    if (t < 128) { uL[t] = u[t]; vL[t] = v[t]; }
    __syncthreads();

    int r0 = (t & 7) * 4;
    int c0 = (t >> 3) * 4;
    float acc[4][4] = {};
    for (int k0 = 0; k0 < 128; k0 += 4) {
        float4 hr[4], wr[4];
        #pragma unroll
        for (int i = 0; i < 4; i++) hr[i] = *(const float4*)&hL[(r0 + i) * 132 + k0];
        #pragma unroll
        for (int i = 0; i < 4; i++) wr[i] = *(const float4*)&wL[(k0 + i) * 132 + c0];
        #pragma unroll
        for (int kj = 0; kj < 4; kj++) {
            #pragma unroll
            for (int ri = 0; ri < 4; ri++) {
                float hvv = ((const float*)&hr[ri])[kj];
                const float* wvv = (const float*)&wr[kj];
                #pragma unroll
                for (int cj = 0; cj < 4; cj++) acc[ri][cj] = fmaf(hvv, wvv[cj], acc[ri][cj]);
            }
        }
    }
    #pragma unroll
    for (int ri = 0; ri < 4; ri++)
        #pragma unroll
        for (int cj = 0; cj < 4; cj++)
            tL[(c0 + cj) * 40 + r0 + ri] = f2b(acc[ri][cj]);
    __syncthreads();

    if (t < 64) {
        int row = t & 31;
        const float* sv = (t < 32) ? uL : vL;
        float s = 0.f;
        for (int k = 0; k < 128; k += 4) {
            float4 h4 = *(const float4*)&hL[row * 132 + k];
            float4 s4 = *(const float4*)&sv[k];
            s = fmaf(h4.x, s4.x, s); s = fmaf(h4.y, s4.y, s);
            s = fmaf(h4.z, s4.z, s); s = fmaf(h4.w, s4.w, s);
        }
        (t < 32 ? e_src : e_dst)[i0 + row] = s;
    }
    // fragment-major writeback: value (f, j) -> WhT2[(j>>5)*4096 + f*32 + (j&31)]
    {
        int f = t & 127, half = t >> 7;
        const uint4* s = (const uint4*)&tL[f * 40 + half * 16];
        uint4* d = (uint4*)&WhT2[(size_t)blockIdx.x * 4096 + f * 32 + half * 16];
        d[0] = s[0]; d[1] = s[1];
    }
}

// ---------------- k1b: adj -> bitmask ----------------
__global__ __launch_bounds__(256) void k1b_bits(const int* __restrict__ adj,
                                                unsigned char* __restrict__ bits) {
    int row = blockIdx.x;
    int t = threadIdx.x;
    int lane = t & 63, wave = t >> 6;
    const int* Ap = adj + (size_t)row * NN;
    #pragma unroll
    for (int i = 0; i < 4; i++) {
        int col = wave * 2048 + i * 512 + lane * 8;
        int4 a0 = *(const int4*)(Ap + col);
        int4 a1 = *(const int4*)(Ap + col + 4);
        unsigned int b =
            (a0.x > 0 ? 1u : 0u)  | (a0.y > 0 ? 2u : 0u) |
            (a0.z > 0 ? 4u : 0u)  | (a0.w > 0 ? 8u : 0u) |
            (a1.x > 0 ? 16u : 0u) | (a1.y > 0 ? 32u : 0u) |
            (a1.z > 0 ? 64u : 0u) | (a1.w > 0 ? 128u : 0u);
        bits[(size_t)row * 1024 + (col >> 3)] = (unsigned char)b;
    }
}

// ---------------- k2 ----------------
__device__ __forceinline__ float wfn(unsigned int bit, float x) {
    float l = fmaxf(x, 0.2f * x);
    float e = __expf(l);
    return bit ? e : 0.f;
}

__global__ __launch_bounds__(256, 4) void k2_gat(const unsigned int* __restrict__ bits,
                                                 const unsigned short* __restrict__ WhT2,
                                                 const float* __restrict__ e_src,
                                                 const float* __restrict__ e_dst,
                                                 float* __restrict__ num_ws,
                                                 float* __restrict__ den_ws) {
    int t = threadIdx.x;
    int bx = blockIdx.x;
    int it = bx >> 4, seg = bx & 15;
    int i0 = it * 128;
    int jb = seg * JSEG;

    int lane = t & 63, wave = t >> 6;
    int mrow = lane & 15, quad = lane >> 4;
    int row0 = i0 + wave * 32 + mrow;
    int row1 = row0 + 16;
    int qs = quad * 8;

    float es0 = e_src[row0];
    float es1 = e_src[row1];
    const unsigned int* bp0 = bits + (size_t)row0 * 256 + (jb >> 5);
    const unsigned int* bp1 = bits + (size_t)row1 * 256 + (jb >> 5);
    // fragment-major B: kappa stride 4096 shorts
    const unsigned short* Bp = WhT2 + (size_t)(jb >> 5) * 4096 + mrow * 32 + qs;
    const float* Ep = e_dst + jb + qs;

    floatx4 acc0[8] = {};
    floatx4 acc1[8] = {};
    float ds0 = 0.f, ds1 = 0.f;

    for (int kg = 0; kg < 4; kg++) {
        uint4 bm0 = *(const uint4*)(bp0 + kg * 4);
        uint4 bm1 = *(const uint4*)(bp1 + kg * 4);
        #pragma unroll
        for (int kq = 0; kq < 4; kq++) {
            int ks = kg * 4 + kq;
            unsigned int byt0 = ((&bm0.x)[kq] >> qs) & 0xFFu;
            unsigned int byt1 = ((&bm1.x)[kq] >> qs) & 0xFFu;
            float4 e0 = *(const float4*)(Ep + ks * 32);
            float4 e1 = *(const float4*)(Ep + ks * 32 + 4);

            float w00 = wfn(byt0 & 1u,   es0 + e0.x);
            float w01 = wfn(byt0 & 2u,   es0 + e0.y);
            float w02 = wfn(byt0 & 4u,   es0 + e0.z);
            float w03 = wfn(byt0 & 8u,   es0 + e0.w);
            float w04 = wfn(byt0 & 16u,  es0 + e1.x);
            float w05 = wfn(byt0 & 32u,  es0 + e1.y);
            float w06 = wfn(byt0 & 64u,  es0 + e1.z);
            float w07 = wfn(byt0 & 128u, es0 + e1.w);
            float w10 = wfn(byt1 & 1u,   es1 + e0.x);
            float w11 = wfn(byt1 & 2u,   es1 + e0.y);
            float w12 = wfn(byt1 & 4u,   es1 + e0.z);
            float w13 = wfn(byt1 & 8u,   es1 + e0.w);
            float w14 = wfn(byt1 & 16u,  es1 + e1.x);
            float w15 = wfn(byt1 & 32u,  es1 + e1.y);
            float w16 = wfn(byt1 & 64u,  es1 + e1.z);
            float w17 = wfn(byt1 & 128u, es1 + e1.w);

            ds0 += ((w00 + w01) + (w02 + w03)) + ((w04 + w05) + (w06 + w07));
            ds1 += ((w10 + w11) + (w12 + w13)) + ((w14 + w15) + (w16 + w17));

            union { unsigned int u[4]; bf16x8 v; } A0, A1;
            A0.u[0] = pk2(w00, w01); A0.u[1] = pk2(w02, w03);
            A0.u[2] = pk2(w04, w05); A0.u[3] = pk2(w06, w07);
            A1.u[0] = pk2(w10, w11); A1.u[1] = pk2(w12, w13);
            A1.u[2] = pk2(w14, w15); A1.u[3] = pk2(w16, w17);

            const unsigned short* pk = Bp + ks * 4096;
            bf16x8 B0 = *(const bf16x8*)(pk);
            bf16x8 B1 = *(const bf16x8*)(pk + 512);
            bf16x8 B2 = *(const bf16x8*)(pk + 1024);
            bf16x8 B3 = *(const bf16x8*)(pk + 1536);
            acc0[0] = __builtin_amdgcn_mfma_f32_16x16x32_bf16(A0.v, B0, acc0[0], 0, 0, 0);
            acc1[0] = __builtin_amdgcn_mfma_f32_16x16x32_bf16(A1.v, B0, acc1[0], 0, 0, 0);
            acc0[1] = __builtin_amdgcn_mfma_f32_16x16x32_bf16(A0.v, B1, acc0[1], 0, 0, 0);
            acc1[1] = __builtin_amdgcn_mfma_f32_16x16x32_bf16(A1.v, B1, acc1[1], 0, 0, 0);
            acc0[2] = __builtin_amdgcn_mfma_f32_16x16x32_bf16(A0.v, B2, acc0[2], 0, 0, 0);
            acc1[2] = __builtin_amdgcn_mfma_f32_16x16x32_bf16(A1.v, B2, acc1[2], 0, 0, 0);
            acc0[3] = __builtin_amdgcn_mfma_f32_16x16x32_bf16(A0.v, B3, acc0[3], 0, 0, 0);
            acc1[3] = __builtin_amdgcn_mfma_f32_16x16x32_bf16(A1.v, B3, acc1[3], 0, 0, 0);
            bf16x8 B4 = *(const bf16x8*)(pk + 2048);
            bf16x8 B5 = *(const bf16x8*)(pk + 2560);
            bf16x8 B6 = *(const bf16x8*)(pk + 3072);
            bf16x8 B7 = *(const bf16x8*)(pk + 3584);
            acc0[4] = __builtin_amdgcn_mfma_f32_16x16x32_bf16(A0.v, B4, acc0[4], 0, 0, 0);
            acc1[4] = __builtin_amdgcn_mfma_f32_16x16x32_bf16(A1.v, B4, acc1[4], 0, 0, 0);
            acc0[5] = __builtin_amdgcn_mfma_f32_16x16x32_bf16(A0.v, B5, acc0[5], 0, 0, 0);
            acc1[5] = __builtin_amdgcn_mfma_f32_16x16x32_bf16(A1.v, B5, acc1[5], 0, 0, 0);
            acc0[6] = __builtin_amdgcn_mfma_f32_16x16x32_bf16(A0.v, B6, acc0[6], 0, 0, 0);
            acc1[6] = __builtin_amdgcn_mfma_f32_16x16x32_bf16(A1.v, B6, acc1[6], 0, 0, 0);
            acc0[7] = __builtin_amdgcn_mfma_f32_16x16x32_bf16(A0.v, B7, acc0[7], 0, 0, 0);
            acc1[7] = __builtin_amdgcn_mfma_f32_16x16x32_bf16(A1.v, B7, acc1[7], 0, 0, 0);
        }
    }

    // denominators: reduce over quads
    ds0 += __shfl_xor(ds0, 16);
    ds0 += __shfl_xor(ds0, 32);
    ds1 += __shfl_xor(ds1, 16);
    ds1 += __shfl_xor(ds1, 32);
    if (quad == 0) {
        den_ws[seg * NN + row0] = ds0;
        den_ws[seg * NN + row1] = ds1;
    }

    // numerator partials (C/D: col = lane&15, row = quad*4 + r)
    float* np = num_ws + (size_t)seg * NN * FF;
    #pragma unroll
    for (int bn = 0; bn < 8; bn++)
        #pragma unroll
        for (int r = 0; r < 4; r++) {
            int orow = i0 + wave * 32 + quad * 4 + r;
            np[(size_t)orow * FF + bn * 16 + mrow] = acc0[bn][r];
            np[(size_t)(orow + 16) * FF + bn * 16 + mrow] = acc1[bn][r];
        }
}

// ---------------- k3: merge seg partials, divide ----------------
__global__ __launch_bounds__(256) void k3_merge(const float* __restrict__ num_ws,
                                               const float* __restrict__ den_ws,
                                               float* __restrict__ out) {
    int idx = blockIdx.x * 256 + threadIdx.x;
    int i = idx >> 5;
    int c = (idx & 31) << 2;
    float4 s = make_float4(0.f, 0.f, 0.f, 0.f);
    float d = 0.f;
    #pragma unroll
    for (int sg = 0; sg < SEGS; sg++) {
        float4 vv = *(const float4*)&num_ws[(size_t)sg * NN * FF + (size_t)i * FF + c];
        s.x += vv.x; s.y += vv.y; s.z += vv.z; s.w += vv.w;
        d += den_ws[sg * NN + i];
    }
    float r = 1.0f / d;
    s.x *= r; s.y *= r; s.z *= r; s.w *= r;
    *(float4*)&out[(size_t)i * FF + c] = s;
}

extern "C" void kernel_launch(void* const* d_in, const int* in_sizes, int n_in,
                              void* d_out, int out_size, void* d_ws, size_t ws_size,
                              hipStream_t stream) {
    const float* h   = (const float*)d_in[0];
    const int*   adj = (const int*)d_in[1];
    const float* W   = (const float*)d_in[2];
    const float* a   = (const float*)d_in[3];
    float* out = (float*)d_out;

    char* ws = (char*)d_ws;
    unsigned short* WhT2 = (unsigned short*)ws;                 // 2 MB exactly
    float* u     = (float*)(ws + 2097152);
    float* v     = u + 128;
    float* e_src = (float*)(ws + 2097152 + 1024);
    float* e_dst = e_src + NN;
    unsigned char* bits = (unsigned char*)(ws + 3145728);       // 8 MB
    float* num_ws = (float*)(ws + 16777216);                    // 64 MB
    float* den_ws = (float*)(ws + 16777216 + 67108864);         // 512 KB

    k0_uv<<<dim3(128), dim3(128), 0, stream>>>(W, a, u, v);
    k1_wh<<<dim3(256), dim3(256), 0, stream>>>(h, W, u, v, WhT2, e_src, e_dst);
    k1b_bits<<<dim3(NN), dim3(256), 0, stream>>>(adj, bits);
    k2_gat<<<dim3((NN / 128) * SEGS), dim3(256), 0, stream>>>((const unsigned int*)bits, WhT2, e_src, e_dst, num_ws, den_ws);
    k3_merge<<<dim3(NN * FF / 4 / 256), dim3(256), 0, stream>>>(num_ws, den_ws, out);
}

// Round 7
// 469.602 us; speedup vs baseline: 1.1171x; 1.1171x over previous
//
#include <hip/hip_runtime.h>
#include <hip/hip_bf16.h>

// GAT layer, N=8192, F=128.
//   k0:  u = W@a1, v = W@a2                    (fp32, trivial)
//   k1:  Wh = h@W -> WhT2 (bf16, fragment-major [kappa][f][k32], kappa
//        stride 4096 shorts);  e_src = h@u, e_dst = h@v (fp32)
//   k1b: adj (256 MB) -> natural-order bitmask (8 MB). Pure streaming.
//   k2:  fused masked-softmax(P) @ Wh via MFMA. Wave = 16 rows x 128 cols,
//        acc[8]=32 VGPR, explicit B double-buffer (Bcur/Bnxt), zero barriers,
//        launch_bounds(512,4) -> 2 blocks/CU. Per-seg partials -> ws.
//   k3:  out = (sum_seg num) / (sum_seg den)
//
// ws: 0-2M WhT2 | 2M u,v | 2M+1K e_src | +32K e_dst | 3M bits (8MB)
//     | 16M num_ws (16 x 4MB) | 80M den_ws (512KB)

#define NN 8192
#define FF 128
#define SEGS 16
#define JSEG (NN / SEGS)     // 512

typedef __bf16 bf16x8 __attribute__((ext_vector_type(8)));
typedef float floatx4 __attribute__((ext_vector_type(4)));

__device__ __forceinline__ unsigned short f2b(float f) {
    unsigned int u = __float_as_uint(f);
    return (unsigned short)((u + 0x7FFFu + ((u >> 16) & 1u)) >> 16);
}

// ---------------- k0 ----------------
__global__ __launch_bounds__(128) void k0_uv(const float* __restrict__ W,
                                             const float* __restrict__ a,
                                             float* __restrict__ u,
                                             float* __restrict__ v) {
    int k = blockIdx.x, t = threadIdx.x;
    float wv = W[k * FF + t];
    float p1 = wv * a[t];
    float p2 = wv * a[FF + t];
    for (int off = 32; off; off >>= 1) {
        p1 += __shfl_down(p1, off);
        p2 += __shfl_down(p2, off);
    }
    __shared__ float r[4];
    if ((t & 63) == 0) { r[(t >> 6) * 2] = p1; r[(t >> 6) * 2 + 1] = p2; }
    __syncthreads();
    if (t == 0) { u[k] = r[0] + r[2]; v[k] = r[1] + r[3]; }
}

// ---------------- k1 ----------------
__global__ __launch_bounds__(256) void k1_wh(const float* __restrict__ h,
                                             const float* __restrict__ W,
                                             const float* __restrict__ u,
                                             const float* __restrict__ v,
                                             unsigned short* __restrict__ WhT2,
                                             float* __restrict__ e_src,
                                             float* __restrict__ e_dst) {
    __shared__ float hL[32 * 132];
    __shared__ float wL[128 * 132];
    __shared__ float uL[128], vL[128];
    __shared__ unsigned short tL[128 * 40];

    int t = threadIdx.x;
    int i0 = blockIdx.x * 32;

    {
        int row = t >> 3, c = (t & 7) * 16;
        const float4* s = (const float4*)&h[(i0 + row) * FF + c];
        float4* d = (float4*)&hL[row * 132 + c];
        #pragma unroll
        for (int j = 0; j < 4; j++) d[j] = s[j];
    }
    {
        int row = t >> 1, c = (t & 1) * 64;
        const float4* s = (const float4*)&W[row * FF + c];
        float4* d = (float4*)&wL[row * 132 + c];
        #pragma unroll
        for (int j = 0; j < 16; j++) d[j] = s[j];
    }
    if (t < 128) { uL[t] = u[t]; vL[t] = v[t]; }
    __syncthreads();

    int r0 = (t & 7) * 4;
    int c0 = (t >> 3) * 4;
    float acc[4][4] = {};
    for (int k0 = 0; k0 < 128; k0 += 4) {
        float4 hr[4], wr[4];
        #pragma unroll
        for (int i = 0; i < 4; i++) hr[i] = *(const float4*)&hL[(r0 + i) * 132 + k0];
        #pragma unroll
        for (int i = 0; i < 4; i++) wr[i] = *(const float4*)&wL[(k0 + i) * 132 + c0];
        #pragma unroll
        for (int kj = 0; kj < 4; kj++) {
            #pragma unroll
            for (int ri = 0; ri < 4; ri++) {
                float hvv = ((const float*)&hr[ri])[kj];
                const float* wvv = (const float*)&wr[kj];
                #pragma unroll
                for (int cj = 0; cj < 4; cj++) acc[ri][cj] = fmaf(hvv, wvv[cj], acc[ri][cj]);
            }
        }
    }
    #pragma unroll
    for (int ri = 0; ri < 4; ri++)
        #pragma unroll
        for (int cj = 0; cj < 4; cj++)
            tL[(c0 + cj) * 40 + r0 + ri] = f2b(acc[ri][cj]);
    __syncthreads();

    if (t < 64) {
        int row = t & 31;
        const float* sv = (t < 32) ? uL : vL;
        float s = 0.f;
        for (int k = 0; k < 128; k += 4) {
            float4 h4 = *(const float4*)&hL[row * 132 + k];
            float4 s4 = *(const float4*)&sv[k];
            s = fmaf(h4.x, s4.x, s); s = fmaf(h4.y, s4.y, s);
            s = fmaf(h4.z, s4.z, s); s = fmaf(h4.w, s4.w, s);
        }
        (t < 32 ? e_src : e_dst)[i0 + row] = s;
    }
    // fragment-major writeback: (f, j) -> WhT2[(j>>5)*4096 + f*32 + (j&31)]
    {
        int f = t & 127, half = t >> 7;
        const uint4* s = (const uint4*)&tL[f * 40 + half * 16];
        uint4* d = (uint4*)&WhT2[(size_t)blockIdx.x * 4096 + f * 32 + half * 16];
        d[0] = s[0]; d[1] = s[1];
    }
}

// ---------------- k1b: adj -> bitmask ----------------
__global__ __launch_bounds__(256) void k1b_bits(const int* __restrict__ adj,
                                                unsigned char* __restrict__ bits) {
    int row = blockIdx.x;
    int t = threadIdx.x;
    int lane = t & 63, wave = t >> 6;
    const int* Ap = adj + (size_t)row * NN;
    #pragma unroll
    for (int i = 0; i < 4; i++) {
        int col = wave * 2048 + i * 512 + lane * 8;
        int4 a0 = *(const int4*)(Ap + col);
        int4 a1 = *(const int4*)(Ap + col + 4);
        unsigned int b =
            (a0.x > 0 ? 1u : 0u)  | (a0.y > 0 ? 2u : 0u) |
            (a0.z > 0 ? 4u : 0u)  | (a0.w > 0 ? 8u : 0u) |
            (a1.x > 0 ? 16u : 0u) | (a1.y > 0 ? 32u : 0u) |
            (a1.z > 0 ? 64u : 0u) | (a1.w > 0 ? 128u : 0u);
        bits[(size_t)row * 1024 + (col >> 3)] = (unsigned char)b;
    }
}

// ---------------- k2 ----------------
__device__ __forceinline__ float wfn(unsigned int bit, float x) {
    float l = fmaxf(x, 0.2f * x);
    float e = __expf(l);
    return bit ? e : 0.f;
}

__device__ __forceinline__ void loadB(bf16x8 B[8], const unsigned short* pk) {
    #pragma unroll
    for (int bn = 0; bn < 8; bn++) B[bn] = *(const bf16x8*)(pk + bn * 512);
}

__global__ __launch_bounds__(512, 4) void k2_gat(const unsigned int* __restrict__ bits,
                                                 const unsigned short* __restrict__ WhT2,
                                                 const float* __restrict__ e_src,
                                                 const float* __restrict__ e_dst,
                                                 float* __restrict__ num_ws,
                                                 float* __restrict__ den_ws) {
    int t = threadIdx.x;
    int bx = blockIdx.x;
    int it = bx >> 4, seg = bx & 15;
    int i0 = it * 128;
    int jb = seg * JSEG;

    int lane = t & 63, wave = t >> 6;
    int mrow = lane & 15, quad = lane >> 4;
    int qs = quad * 8;
    int row = i0 + wave * 16 + mrow;      // each row owned by exactly one wave

    float es = e_src[row];
    const unsigned int* bp = bits + (size_t)row * 256 + (jb >> 5);
    const unsigned short* Bp = WhT2 + (size_t)(jb >> 5) * 4096 + mrow * 32 + qs;
    const float* Ep = e_dst + jb + qs;

    floatx4 acc[8] = {};
    float dsum = 0.f;

    bf16x8 Bcur[8], Bnxt[8];
    loadB(Bcur, Bp);                       // k-step 0 B
    uint4 bm = *(const uint4*)bp;          // k-group 0 masks

    #pragma unroll
    for (int kg = 0; kg < 4; kg++) {
        uint4 bmn = bm;
        if (kg < 3) bmn = *(const uint4*)(bp + (kg + 1) * 4);
        #pragma unroll
        for (int kq = 0; kq < 4; kq++) {
            int ks = kg * 4 + kq;
            // prefetch next k-step's B fragments (wraps at the end; harmless)
            loadB(Bnxt, Bp + ((ks + 1) & 15) * 4096);

            float4 e0 = *(const float4*)(Ep + ks * 32);
            float4 e1 = *(const float4*)(Ep + ks * 32 + 4);
            unsigned int byt = ((&bm.x)[kq] >> qs) & 0xFFu;

            float w0 = wfn(byt & 1u,   es + e0.x);
            float w1 = wfn(byt & 2u,   es + e0.y);
            float w2 = wfn(byt & 4u,   es + e0.z);
            float w3 = wfn(byt & 8u,   es + e0.w);
            float w4 = wfn(byt & 16u,  es + e1.x);
            float w5 = wfn(byt & 32u,  es + e1.y);
            float w6 = wfn(byt & 64u,  es + e1.z);
            float w7 = wfn(byt & 128u, es + e1.w);
            dsum += ((w0 + w1) + (w2 + w3)) + ((w4 + w5) + (w6 + w7));

            bf16x8 A;
            A[0] = (__bf16)w0; A[1] = (__bf16)w1;
            A[2] = (__bf16)w2; A[3] = (__bf16)w3;
            A[4] = (__bf16)w4; A[5] = (__bf16)w5;
            A[6] = (__bf16)w6; A[7] = (__bf16)w7;

            #pragma unroll
            for (int bn = 0; bn < 8; bn++)
                acc[bn] = __builtin_amdgcn_mfma_f32_16x16x32_bf16(A, Bcur[bn], acc[bn], 0, 0, 0);

            #pragma unroll
            for (int bn = 0; bn < 8; bn++) Bcur[bn] = Bnxt[bn];
        }
        bm = bmn;
    }

    // denominator: reduce this row's partial over the 4 quads
    dsum += __shfl_xor(dsum, 16);
    dsum += __shfl_xor(dsum, 32);
    if (quad == 0) den_ws[seg * NN + row] = dsum;

    // numerator partials (C/D: col = lane&15, row = quad*4 + r)
    float* np = num_ws + (size_t)seg * NN * FF;
    #pragma unroll
    for (int bn = 0; bn < 8; bn++)
        #pragma unroll
        for (int r = 0; r < 4; r++) {
            int orow = i0 + wave * 16 + quad * 4 + r;
            np[(size_t)orow * FF + bn * 16 + mrow] = acc[bn][r];
        }
}

// ---------------- k3: merge seg partials, divide ----------------
__global__ __launch_bounds__(256) void k3_merge(const float* __restrict__ num_ws,
                                               const float* __restrict__ den_ws,
                                               float* __restrict__ out) {
    int idx = blockIdx.x * 256 + threadIdx.x;
    int i = idx >> 5;
    int c = (idx & 31) << 2;
    float4 s = make_float4(0.f, 0.f, 0.f, 0.f);
    float d = 0.f;
    #pragma unroll
    for (int sg = 0; sg < SEGS; sg++) {
        float4 vv = *(const float4*)&num_ws[(size_t)sg * NN * FF + (size_t)i * FF + c];
        s.x += vv.x; s.y += vv.y; s.z += vv.z; s.w += vv.w;
        d += den_ws[sg * NN + i];
    }
    float r = 1.0f / d;
    s.x *= r; s.y *= r; s.z *= r; s.w *= r;
    *(float4*)&out[(size_t)i * FF + c] = s;
}

extern "C" void kernel_launch(void* const* d_in, const int* in_sizes, int n_in,
                              void* d_out, int out_size, void* d_ws, size_t ws_size,
                              hipStream_t stream) {
    const float* h   = (const float*)d_in[0];
    const int*   adj = (const int*)d_in[1];
    const float* W   = (const float*)d_in[2];
    const float* a   = (const float*)d_in[3];
    float* out = (float*)d_out;

    char* ws = (char*)d_ws;
    unsigned short* WhT2 = (unsigned short*)ws;                 // 2 MB exactly
    float* u     = (float*)(ws + 2097152);
    float* v     = u + 128;
    float* e_src = (float*)(ws + 2097152 + 1024);
    float* e_dst = e_src + NN;
    unsigned char* bits = (unsigned char*)(ws + 3145728);       // 8 MB
    float* num_ws = (float*)(ws + 16777216);                    // 64 MB
    float* den_ws = (float*)(ws + 16777216 + 67108864);         // 512 KB

    k0_uv<<<dim3(128), dim3(128), 0, stream>>>(W, a, u, v);
    k1_wh<<<dim3(256), dim3(256), 0, stream>>>(h, W, u, v, WhT2, e_src, e_dst);
    k1b_bits<<<dim3(NN), dim3(256), 0, stream>>>(adj, bits);
    k2_gat<<<dim3((NN / 128) * SEGS), dim3(512), 0, stream>>>((const unsigned int*)bits, WhT2, e_src, e_dst, num_ws, den_ws);
    k3_merge<<<dim3(NN * FF / 4 / 256), dim3(256), 0, stream>>>(num_ws, den_ws, out);
}